// Round 1
// baseline (69.250 us; speedup 1.0000x reference)
//
#include <hip/hip_runtime.h>

// Problem constants (from setup_inputs): N=8, C=1024, D=128, K=64, R=256
#define N_ 8
#define C_ 1024
#define D_ 128
#define K_ 64
#define R_ 256

// out[n,c,k,d] = (xhat[n,c,d] - cent[n,k,d]) / (8 * ||xhat[n,c]-cent[n,k]||)
// where xhat = x / max(||x||, eps), cent[n,k] = cluster[n, cluster_idx[k]].
// The softmax in the reference cancels exactly under the per-k l2norm, and the
// final l2norm over K*D is exactly sqrt(K)=8 (K unit vectors concatenated).
__global__ __launch_bounds__(256) void vlad_collapse_kernel(
    const float* __restrict__ x,            // (N, C, D)
    const float* __restrict__ cluster,      // (N, R, D)
    const int*   __restrict__ cluster_idx,  // (K,)
    float*       __restrict__ out)          // (N, C, K*D)
{
    __shared__ __align__(16) float xhat[D_];
    __shared__ float invdist[K_];
    __shared__ int   sidx[K_];
    __shared__ float dred[4][K_];
    __shared__ float wred[4];
    __shared__ float rinv;

    const int blk = blockIdx.x;          // n*C + c
    const int n   = blk >> 10;           // / C_
    const int t   = threadIdx.x;

    if (t < K_) sidx[t] = cluster_idx[t];

    // ---- Phase 1: load x row, compute 1/||x|| ----
    const float* xrow = x + (size_t)blk * D_;
    float v = 0.f;
    if (t < D_) { float xv = xrow[t]; xhat[t] = xv; v = xv * xv; }
    float s = v;
    #pragma unroll
    for (int off = 32; off; off >>= 1) s += __shfl_down(s, off, 64);
    if ((t & 63) == 0) wred[t >> 6] = s;   // waves 2,3 contribute 0
    __syncthreads();
    if (t == 0) {
        float tot = wred[0] + wred[1] + wred[2] + wred[3];
        rinv = 1.0f / fmaxf(sqrtf(tot), 1e-12f);
    }
    __syncthreads();
    const float invn = rinv;
    if (t < D_) xhat[t] *= invn;         // own element, no extra barrier needed
    __syncthreads();

    // ---- Phase 2: dist^2(xhat, cent_k) for all k; (k = lane, quarter = wave) ----
    {
        const int k = t & 63;
        const int q = t >> 6;
        const float* centk = cluster + ((size_t)n * R_ + sidx[k]) * D_ + q * 32;
        const float* xq = xhat + q * 32;
        float ds = 0.f;
        #pragma unroll
        for (int j = 0; j < 32; ++j) {
            float diff = xq[j] - centk[j];   // xq[j]: wave-uniform LDS broadcast
            ds = fmaf(diff, diff, ds);
        }
        dred[q][k] = ds;
    }
    __syncthreads();
    if (t < K_) {
        float tot = dred[0][t] + dred[1][t] + dred[2][t] + dred[3][t];
        invdist[t] = 0.125f / fmaxf(sqrtf(tot), 1e-12f);   // includes 1/sqrt(K)
    }
    __syncthreads();

    // ---- Phase 3: stream the (K,D) tile = 8192 floats = 2048 float4 stores ----
    float* orow = out + (size_t)blk * (K_ * D_);
    #pragma unroll
    for (int it = 0; it < 8; ++it) {
        const int j  = it * 256 + t;     // float4 index within the tile
        const int kk = j >> 5;           // D/4 = 32 float4 per k
        const int d4 = j & 31;
        const float* cent = cluster + ((size_t)n * R_ + sidx[kk]) * D_ + d4 * 4;
        const float4 cv = *(const float4*)cent;
        const float4 xv = *(const float4*)(xhat + d4 * 4);
        const float id = invdist[kk];
        float4 o;
        o.x = (xv.x - cv.x) * id;
        o.y = (xv.y - cv.y) * id;
        o.z = (xv.z - cv.z) * id;
        o.w = (xv.w - cv.w) * id;
        *(float4*)(orow + (size_t)j * 4) = o;
    }
}

extern "C" void kernel_launch(void* const* d_in, const int* in_sizes, int n_in,
                              void* d_out, int out_size, void* d_ws, size_t ws_size,
                              hipStream_t stream) {
    const float* x           = (const float*)d_in[0];
    const float* cluster     = (const float*)d_in[1];
    // d_in[2] = conv_w, d_in[3] = conv_b: mathematically cancelled, unused.
    const int*   cluster_idx = (const int*)d_in[4];
    float* out = (float*)d_out;

    dim3 grid(N_ * C_), block(256);
    vlad_collapse_kernel<<<grid, block, 0, stream>>>(x, cluster, cluster_idx, out);
}

// Round 2
// 57.027 us; speedup vs baseline: 1.2143x; 1.2143x over previous
//
#include <hip/hip_runtime.h>

// Problem constants: N=8, C=1024, D=128, K=64, R=256
#define N_ 8
#define C_ 1024
#define D_ 128
#define K_ 64
#define R_ 256

// out[n,c,k,d] = (xhat[n,c,d] - cent[n,k,d]) / (8 * ||xhat[n,c]-cent[n,k]||)
// xhat = x/max(||x||,eps), cent[n,k] = cluster[n, cluster_idx[k]].
// Softmax cancels exactly under the per-k l2norm; final l2norm over K*D is
// exactly sqrt(K)=8 (K unit vectors concatenated).
//
// Thread mapping: block = one (n,c) row, 256 threads = 8 half-waves.
// half-wave h owns k = p*8+h for p in 0..7; lane l owns d-slice [4l, 4l+4).
// All cross-lane reduction via 32-lane xor butterflies -> no LDS, no barriers.
__global__ __launch_bounds__(256) void vlad_stream_kernel(
    const float* __restrict__ x,            // (N, C, D)
    const float* __restrict__ cluster,      // (N, R, D)
    const int*   __restrict__ cluster_idx,  // (K,)
    float*       __restrict__ out)          // (N, C, K*D)
{
    const int blk = blockIdx.x;      // n*C + c
    const int n   = blk >> 10;
    const int t   = threadIdx.x;
    const int l   = t & 31;          // lane within half-wave
    const int h   = t >> 5;          // half-wave id 0..7

    // ---- x row: each half-wave holds the full 128-float row in its 32 lanes ----
    const float* xrow = x + (size_t)blk * D_;
    float4 xv = *(const float4*)(xrow + l * 4);          // coalesced, L1-broadcast

    float nx = fmaf(xv.x, xv.x, fmaf(xv.y, xv.y, fmaf(xv.z, xv.z, xv.w * xv.w)));
    #pragma unroll
    for (int m = 1; m <= 16; m <<= 1) nx += __shfl_xor(nx, m, 32);
    const float rinv = 1.0f / fmaxf(sqrtf(nx), 1e-12f);
    xv.x *= rinv; xv.y *= rinv; xv.z *= rinv; xv.w *= rinv;

    // ---- distances: 8 passes, half-wave h handles k = p*8+h, coalesced row reads ----
    const float* cbase = cluster + (size_t)n * (R_ * D_);
    float4 diff[8];
    float  id[8];
    #pragma unroll
    for (int p = 0; p < 8; ++p) {
        const int k = p * 8 + h;
        const float4 cv = *(const float4*)(cbase + (size_t)cluster_idx[k] * D_ + l * 4);
        float4 d;
        d.x = xv.x - cv.x; d.y = xv.y - cv.y;
        d.z = xv.z - cv.z; d.w = xv.w - cv.w;
        diff[p] = d;
        float ds = fmaf(d.x, d.x, fmaf(d.y, d.y, fmaf(d.z, d.z, d.w * d.w)));
        #pragma unroll
        for (int m = 1; m <= 16; m <<= 1) ds += __shfl_xor(ds, m, 32);
        // butterfly leaves the full sum in every lane
        id[p] = 0.125f / fmaxf(sqrtf(ds), 1e-12f);       // includes 1/sqrt(K)
    }

    // ---- stream the (K,D) tile: 8 coalesced float4 stores per thread ----
    // float4 index for pass p is p*256 + t  ->  k = (p*256+t)>>5 = p*8+h  (matches)
    float* orow = out + (size_t)blk * (K_ * D_) + (size_t)t * 4;
    #pragma unroll
    for (int p = 0; p < 8; ++p) {
        float4 o;
        o.x = diff[p].x * id[p];
        o.y = diff[p].y * id[p];
        o.z = diff[p].z * id[p];
        o.w = diff[p].w * id[p];
        *(float4*)(orow + (size_t)p * 1024) = o;
    }
}

extern "C" void kernel_launch(void* const* d_in, const int* in_sizes, int n_in,
                              void* d_out, int out_size, void* d_ws, size_t ws_size,
                              hipStream_t stream) {
    const float* x           = (const float*)d_in[0];
    const float* cluster     = (const float*)d_in[1];
    // d_in[2] = conv_w, d_in[3] = conv_b: mathematically cancelled, unused.
    const int*   cluster_idx = (const int*)d_in[4];
    float* out = (float*)d_out;

    dim3 grid(N_ * C_), block(256);
    vlad_stream_kernel<<<grid, block, 0, stream>>>(x, cluster, cluster_idx, out);
}